// Round 1
// baseline (588.548 us; speedup 1.0000x reference)
//
#include <hip/hip_runtime.h>
#include <hip/hip_bf16.h>
#include <stdint.h>

// MoE LoRA: N=16384, D_IN=4096, D_OUT=4096, RANK=64, TOPK=8.
// Two-kernel restructure (v2):
//   A) compute_s: one row per WAVE, gathered dots vs down_w, scaled -> d_ws.
//   B) up_proj:   256-col slice of up_w staged in LDS (transposed, pad 65),
//                 reused across 128 rows -> cuts up_w L2 traffic 16x.
// Dtype self-detection kept from v1 (probe sets device flags; fp32/bf16 paths).
#define NROWS 16384
#define D_IN  4096
#define D_OUT 4096
#define RANK  64
#define TOPK  8

// kernel B tiling
#define BCOLS 256
#define BROWS 128
#define LSTRIDE 65   // 64+1 pad: LDS word = t*65 + r -> bank (t + r) & 31, conflict-free

typedef __hip_bfloat16 bf16;

__device__ int g_is_fp32;   // 1 if tensors are fp32, 0 if bf16
__device__ int g_idx64;     // 1 if indices are int64 on device, 0 if int32

__device__ __forceinline__ void unpack8(uint4 raw, float f[8]) {
    const unsigned u0 = raw.x, u1 = raw.y, u2 = raw.z, u3 = raw.w;
    f[0] = __uint_as_float(u0 << 16);
    f[1] = __uint_as_float(u0 & 0xffff0000u);
    f[2] = __uint_as_float(u1 << 16);
    f[3] = __uint_as_float(u1 & 0xffff0000u);
    f[4] = __uint_as_float(u2 << 16);
    f[5] = __uint_as_float(u2 & 0xffff0000u);
    f[6] = __uint_as_float(u3 << 16);
    f[7] = __uint_as_float(u3 & 0xffff0000u);
}

// ---- probe: decide dtypes from raw bits (unchanged from v1, verified) ----
__global__ void probe_dtypes(const unsigned short* __restrict__ hid_u16,
                             const int* __restrict__ idx_i32) {
    if (threadIdx.x != 0 || blockIdx.x != 0) return;
    int plausible = 0;
    for (int i = 0; i < 64; i += 2) {
        int e = (hid_u16[i] >> 7) & 0xff;
        if (e >= 0x70 && e <= 0x8a) plausible++;
    }
    g_is_fp32 = (plausible < 16) ? 1 : 0;
    int oddnz = 0;
    for (int i = 1; i < 64; i += 2)
        if (idx_i32[i] != 0) oddnz++;
    g_idx64 = (oddnz == 0) ? 1 : 0;
}

// ---- Kernel A: s[n][k] = dot(hidden[n], down_w[idx_k]) * val_k ----
// One row per wave; 4 waves/block; no __syncthreads, no LDS -> high occupancy.
__global__ __launch_bounds__(256) void compute_s(
    const void* __restrict__ hidden,     // [N, D_IN]
    const void* __restrict__ down_w,     // [RANK, D_IN]
    const void* __restrict__ topk_vals,  // [N, TOPK]
    const void* __restrict__ topk_idx,   // [N, TOPK]
    float* __restrict__ s_out)           // [N, TOPK]
{
    const int lane = threadIdx.x & 63;
    const int n = blockIdx.x * 4 + (threadIdx.x >> 6);
    const bool fp32 = (g_is_fp32 != 0);
    const bool idx64 = (g_idx64 != 0);

    int idx[TOPK];
#pragma unroll
    for (int k = 0; k < TOPK; ++k) {
        const int m = n * TOPK + k;
        const int v = idx64 ? ((const int*)topk_idx)[2 * m]
                            : ((const int*)topk_idx)[m];
        idx[k] = v & (RANK - 1);   // safety clamp
    }

    float acc[TOPK];
#pragma unroll
    for (int k = 0; k < TOPK; ++k) acc[k] = 0.0f;

    if (fp32) {
        const float* hrow = (const float*)hidden + (size_t)n * D_IN;
        const float* dw   = (const float*)down_w;
#pragma unroll 2
        for (int i = 0; i < D_IN / (64 * 4); ++i) {        // 16 iters
            const int off = i * 256 + lane * 4;
            const float4 h = *reinterpret_cast<const float4*>(hrow + off);
#pragma unroll
            for (int k = 0; k < TOPK; ++k) {
                const float4 w = *reinterpret_cast<const float4*>(dw + (size_t)idx[k] * D_IN + off);
                acc[k] = fmaf(h.x, w.x, acc[k]);
                acc[k] = fmaf(h.y, w.y, acc[k]);
                acc[k] = fmaf(h.z, w.z, acc[k]);
                acc[k] = fmaf(h.w, w.w, acc[k]);
            }
        }
    } else {
        const bf16* hrow = (const bf16*)hidden + (size_t)n * D_IN;
        const bf16* dw   = (const bf16*)down_w;
#pragma unroll 2
        for (int i = 0; i < D_IN / (64 * 8); ++i) {        // 8 iters
            const int off = i * 512 + lane * 8;
            float h[8];
            unpack8(*reinterpret_cast<const uint4*>(hrow + off), h);
#pragma unroll
            for (int k = 0; k < TOPK; ++k) {
                float w[8];
                unpack8(*reinterpret_cast<const uint4*>(dw + (size_t)idx[k] * D_IN + off), w);
#pragma unroll
                for (int j = 0; j < 8; ++j) acc[k] = fmaf(h[j], w[j], acc[k]);
            }
        }
    }

    // 64-lane butterfly reduce each acc; lane k keeps sum k
    float mys = 0.0f;
#pragma unroll
    for (int k = 0; k < TOPK; ++k) {
        float v = acc[k];
#pragma unroll
        for (int d = 32; d > 0; d >>= 1) v += __shfl_xor(v, d, 64);
        if (lane == k) mys = v;
    }
    if (lane < TOPK) {
        const int m = n * TOPK + lane;
        const float scale = fp32 ? ((const float*)topk_vals)[m]
                                 : __bfloat162float(((const bf16*)topk_vals)[m]);
        s_out[m] = mys * scale;
    }
}

// ---- Kernel B: out[n, c] = sum_k s[n][k] * up_w[c][idx_k] ----
// Block owns cols [c0, c0+256) x rows [n0, n0+128). up_w slice transposed
// into LDS once (64 KB from L2), then 128 rows served from LDS.
__global__ __launch_bounds__(256) void up_proj(
    const void* __restrict__ up_w,      // [D_OUT, RANK]
    const float* __restrict__ s_in,     // [N, TOPK] (scaled)
    const void* __restrict__ topk_idx,  // [N, TOPK]
    void* __restrict__ out)             // [N, D_OUT]
{
    const int t = threadIdx.x;
    const int c0 = (blockIdx.x & (D_OUT / BCOLS - 1)) * BCOLS;    // 16 col tiles
    const int n0 = (blockIdx.x / (D_OUT / BCOLS)) * BROWS;
    const bool fp32 = (g_is_fp32 != 0);
    const bool idx64 = (g_idx64 != 0);

    __shared__ float s_up[BCOLS * LSTRIDE];   // 66,560 B: s_up[col][rank], pad 65
    __shared__ float s_s[BROWS][TOPK];        // 4 KB
    __shared__ int   s_i[BROWS][TOPK];        // 4 KB

    // stage up_w rows c0..c0+255 (contiguous 64 KB chunk), transposing into LDS
    if (fp32) {
        const float4* src = reinterpret_cast<const float4*>(
            (const float*)up_w + (size_t)c0 * RANK);
#pragma unroll
        for (int j = 0; j < (BCOLS * RANK) / (4 * 256); ++j) {    // 16
            const int m = j * 256 + t;         // float4 index
            const float4 v = src[m];
            const int o = m >> 4;              // col within tile (16 float4/col)
            const int r = (m & 15) * 4;        // rank
            float* dst = s_up + o * LSTRIDE + r;
            dst[0] = v.x; dst[1] = v.y; dst[2] = v.z; dst[3] = v.w;
        }
    } else {
        const uint4* src = reinterpret_cast<const uint4*>(
            (const bf16*)up_w + (size_t)c0 * RANK);
#pragma unroll
        for (int j = 0; j < (BCOLS * RANK) / (8 * 256); ++j) {    // 8
            const int m = j * 256 + t;         // uint4 index (8 bf16)
            float f[8];
            unpack8(src[m], f);
            const int o = m >> 3;
            const int r = (m & 7) * 8;
            float* dst = s_up + o * LSTRIDE + r;
#pragma unroll
            for (int jj = 0; jj < 8; ++jj) dst[jj] = f[jj];
        }
    }

    // stage per-row s and idx (uniform broadcast reads later)
#pragma unroll
    for (int j = 0; j < (BROWS * TOPK) / 256; ++j) {              // 4
        const int m = j * 256 + t;
        const int gm = n0 * TOPK + m;
        const int v = idx64 ? ((const int*)topk_idx)[2 * gm]
                            : ((const int*)topk_idx)[gm];
        ((int*)s_i)[m]   = v & (RANK - 1);
        ((float*)s_s)[m] = s_in[gm];
    }
    __syncthreads();

    // each thread owns column c0 + t
    const float* myup = s_up + t * LSTRIDE;
    if (fp32) {
        float* orow = (float*)out + (size_t)n0 * D_OUT + c0 + t;
#pragma unroll 4
        for (int row = 0; row < BROWS; ++row) {
            float a = 0.0f;
#pragma unroll
            for (int k = 0; k < TOPK; ++k)
                a = fmaf(s_s[row][k], myup[s_i[row][k]], a);
            orow[(size_t)row * D_OUT] = a;
        }
    } else {
        bf16* orow = (bf16*)out + (size_t)n0 * D_OUT + c0 + t;
#pragma unroll 4
        for (int row = 0; row < BROWS; ++row) {
            float a = 0.0f;
#pragma unroll
            for (int k = 0; k < TOPK; ++k)
                a = fmaf(s_s[row][k], myup[s_i[row][k]], a);
            orow[(size_t)row * D_OUT] = __float2bfloat16(a);
        }
    }
}

extern "C" void kernel_launch(void* const* d_in, const int* in_sizes, int n_in,
                              void* d_out, int out_size, void* d_ws, size_t ws_size,
                              hipStream_t stream) {
    const void* hidden = d_in[0];   // [N, D_IN]
    const void* down_w = d_in[1];   // [RANK, D_IN]
    const void* up_w   = d_in[2];   // [D_OUT, RANK]
    const void* vals   = d_in[3];   // [N, TOPK]
    const void* idx    = d_in[4];   // [N, TOPK]
    float* s_ws = (float*)d_ws;     // [N, TOPK] fp32 = 512 KB

    probe_dtypes<<<1, 64, 0, stream>>>((const unsigned short*)hidden, (const int*)idx);
    compute_s<<<NROWS / 4, 256, 0, stream>>>(hidden, down_w, vals, idx, s_ws);
    up_proj<<<(D_OUT / BCOLS) * (NROWS / BROWS), 256, 0, stream>>>(up_w, s_ws, idx, d_out);
}